// Round 10
// baseline (1995.104 us; speedup 1.0000x reference)
//
#include <hip/hip_runtime.h>
#include <hip/hip_bf16.h>
#include <math.h>

#define NEGV -1e9f
#define NEGH -5e8f

typedef __attribute__((ext_vector_type(8))) short short8;
typedef __attribute__((ext_vector_type(4))) float f32x4;

__device__ __forceinline__ unsigned fkey(float f) {
  unsigned u = __float_as_uint(f);
  return (u & 0x80000000u) ? ~u : (u | 0x80000000u);
}
__device__ __forceinline__ unsigned long long key48(float s, int j) {
  return ((unsigned long long)fkey(s) << 15) | (unsigned long long)(32767 - j);
}
__device__ __forceinline__ unsigned short bf16_rne(float v) {
  unsigned u = __float_as_uint(v);
  unsigned r = u + 0x7FFFu + ((u >> 16) & 1u);
  return (unsigned short)(r >> 16);
}
__device__ __forceinline__ float bf16_f(unsigned short h) {
  return __uint_as_float(((unsigned)h) << 16);
}

#if defined(__has_builtin)
#if __has_builtin(__builtin_amdgcn_global_load_lds)
#define HAS_GLL 1
#endif
#endif

__device__ __forceinline__ void stage16(const char* gsrc_lane, char* ldsbase, int ln) {
#ifdef HAS_GLL
  typedef unsigned int __attribute__((address_space(1))) gu32;
  typedef unsigned int __attribute__((address_space(3))) lu32;
  __builtin_amdgcn_global_load_lds((const gu32*)gsrc_lane, (lu32*)ldsbase, 16, 0, 0);
#else
  *(uint4*)(ldsbase + ln * 16) = *(const uint4*)gsrc_lane;
#endif
}

// ==================================================================
// Tile layout (per plane: rowpairs x 128B):
//   byte(row,k) = (row>>1)*128 + ((((row&1)<<6) + 2k) ^ (((row>>1)&7)<<4))
// W1pack image order: [ct=4][s=144][plane hi/mid/lo][2048 dw]
// ==================================================================

// ------------------------------------------------------------------
// Pack W1 (coalesced): one thread per (oc, cin-pair) reads 72B
// contiguous, writes 27 dwords via the inverse layout map.
// Output bytes identical to the verified round-5..9 packer.
// ------------------------------------------------------------------
__global__ __launch_bounds__(256) void w1pack_kernel(
    const float* __restrict__ W1, unsigned* __restrict__ W1pack) {
  int g = blockIdx.x * 256 + threadIdx.x;   // 512*256 = 131072 exact
  int oc = g >> 8;
  int cp = g & 255;
  int cin = cp * 2;
  int ct = oc >> 7;
  int row = oc & 127;
  float buf[18];
  const float* src = W1 + (size_t)oc * 4608 + cin * 9;
  #pragma unroll
  for (int i = 0; i < 18; ++i) buf[i] = src[i];
  // inverse of the dword->(row,k) map (k = cin&31, even)
  int k = cin & 31;
  int R = row >> 1;
  int val = ((row & 1) << 6) | (k << 1);
  int tb = (R << 7) | (val ^ ((R & 7) << 4));
  int dwimg = tb >> 2;
  int sBase = cp >> 4;                      // cin>>5
  #pragma unroll
  for (int tap = 0; tap < 9; ++tap) {
    float w0 = buf[tap], w1 = buf[9 + tap];
    unsigned short h0 = bf16_rne(w0), h1 = bf16_rne(w1);
    float r0 = w0 - bf16_f(h0), r1 = w1 - bf16_f(h1);
    unsigned short m0 = bf16_rne(r0), m1 = bf16_rne(r1);
    unsigned short l0 = bf16_rne(r0 - bf16_f(m0)), l1 = bf16_rne(r1 - bf16_f(m1));
    int s = tap * 16 + sBase;
    size_t base = ((size_t)(ct * 144 + s) * 3) * 2048 + dwimg;
    W1pack[base]        = (unsigned)h0 | ((unsigned)h1 << 16);
    W1pack[base + 2048] = (unsigned)m0 | ((unsigned)m1 << 16);
    W1pack[base + 4096] = (unsigned)l0 | ((unsigned)l1 << 16);
  }
}

// ------------------------------------------------------------------
// Conv 3x3 as split-3 bf16 MFMA GEMM (math verified rounds 5-9).
// NEW: 128ch x 256pix tile, 512 threads (8 waves of the same 64x64
// wave-tile), pixel axis flattened over (batch,pixel) in [0,20000).
// Halves weight re-fetch: 79 blocks/ct-slice instead of 160.
// LDS: A 24KB (single buf) + B 48KB = 72KB -> 2 blocks/CU.
// ------------------------------------------------------------------
__global__ __launch_bounds__(512) void conv_mfma_kernel(
    const float* __restrict__ feat, const char* __restrict__ W1pack,
    const float* __restrict__ b1, float* __restrict__ conv1) {
  __shared__ char smem[73728];           // A 3x8KB | B 3x16KB
  const int tid = threadIdx.x;
  const int ct = blockIdx.y;
  const int n0 = blockIdx.x * 256;       // global pixel base (b*2500+pix)
  const int wv = tid >> 6, ln = tid & 63;

  // B staging map: thread -> (global pixel, k-half)
  const int spix = tid & 255;
  const int kh   = tid >> 8;             // 0/1 -> k 0..15 / 16..31
  int p = n0 + spix; if (p > 19999) p = 19999;
  const int pb  = p / 2500;
  const int pix = p - pb * 2500;
  const int pyy = pix / 50;
  const int pxx = pix - pyy * 50;
  const float* featb = feat + (size_t)pb * 512 * 2500;
  const char* wsrc = W1pack + (size_t)ct * 144 * 24576;

  // compute mapping: 2(ch) x 4(pix) wave grid, 64x64 per wave
  const int wch0  = (wv >> 2) * 64;
  const int wpix0 = (wv & 3) * 64;
  const int lrow = ln & 15, lg = ln >> 4;

  f32x4 acc[4][4];
  #pragma unroll
  for (int i = 0; i < 4; ++i)
    #pragma unroll
    for (int j = 0; j < 4; ++j) acc[i][j] = (f32x4)0.f;

  float u[16];

  auto loadFeat = [&](int s) {
    int tap = s >> 4;
    int dy = tap / 3, dx = tap - dy * 3;
    int iy = pyy + dy - 1, ix = pxx + dx - 1;
    bool ok = ((unsigned)iy < 50u) && ((unsigned)ix < 50u);
    int cinb = ((s & 15) << 5) + kh * 16;
    const float* base = featb + (size_t)cinb * 2500 + iy * 50 + ix;
    #pragma unroll
    for (int i = 0; i < 16; ++i) u[i] = ok ? base[(size_t)i * 2500] : 0.f;
  };
  auto issueA = [&](int s) {
    const char* src = wsrc + (size_t)s * 24576;
    // 24 chunks of 1KB over 8 waves x 3
    #pragma unroll
    for (int c = 0; c < 3; ++c) {
      int chunk = c * 8 + wv;
      stage16(src + chunk * 1024 + ln * 16, smem + chunk * 1024, ln);
    }
  };
  auto writeB = [&]() {
    unsigned short h[16], m[16], l[16];
    #pragma unroll
    for (int i = 0; i < 16; ++i) {
      float v = u[i];
      h[i] = bf16_rne(v);
      float r1 = v - bf16_f(h[i]);
      m[i] = bf16_rne(r1);
      float r2 = r1 - bf16_f(m[i]);
      l[i] = bf16_rne(r2);
    }
    const int r = spix >> 1;
    const int swz = (r & 7) << 4;
    char* rowb = smem + 24576 + r * 128;
    #pragma unroll
    for (int pl = 0; pl < 3; ++pl) {
      const unsigned short* sp = (pl == 0) ? h : (pl == 1 ? m : l);
      char* pbp = rowb + pl * 16384;
      #pragma unroll
      for (int q = 0; q < 4; ++q) {
        int pre = ((spix & 1) << 6) + kh * 32 + q * 8;
        uint2 w;
        w.x = (unsigned)sp[q*4]   | ((unsigned)sp[q*4+1] << 16);
        w.y = (unsigned)sp[q*4+2] | ((unsigned)sp[q*4+3] << 16);
        *(uint2*)(pbp + (pre ^ swz)) = w;
      }
    }
  };
  auto rdFrag = [&](const char* base, int row) -> short8 {
    int byte = (row >> 1) * 128 +
               ((((row & 1) << 6) + (lg << 4)) ^ (((row >> 1) & 7) << 4));
    return *(const short8*)(base + byte);
  };

  loadFeat(0);
  #pragma unroll 1
  for (int s = 0; s < 144; ++s) {
    __syncthreads();                 // previous compute done with LDS
    issueA(s);
    writeB();
    __syncthreads();                 // drains DMA (vmcnt) + B writes
    if (s + 1 < 144) loadFeat(s + 1);   // flies over compute
    short8 fa[3][4];
    #pragma unroll
    for (int pl = 0; pl < 3; ++pl)
      #pragma unroll
      for (int f = 0; f < 4; ++f)
        fa[pl][f] = rdFrag(smem + pl * 8192, wch0 + f * 16 + lrow);
    #pragma unroll
    for (int jb = 0; jb < 3; ++jb) {
      short8 fb[4];
      #pragma unroll
      for (int f = 0; f < 4; ++f)
        fb[f] = rdFrag(smem + 24576 + jb * 16384, wpix0 + f * 16 + lrow);
      const int na = 3 - jb;
      #pragma unroll
      for (int ap = 0; ap < 3; ++ap) {
        if (ap < na) {
          #pragma unroll
          for (int i = 0; i < 4; ++i)
            #pragma unroll
            for (int j = 0; j < 4; ++j)
              acc[i][j] = __builtin_amdgcn_mfma_f32_16x16x32_bf16(
                  fa[ap][i], fb[j], acc[i][j], 0, 0, 0);
        }
      }
    }
  }

  const int chb = ct * 128 + wch0 + lg * 4;
  #pragma unroll
  for (int i = 0; i < 4; ++i) {
    int ch = chb + i * 16;
    float4 bias = *(const float4*)&b1[ch];
    #pragma unroll
    for (int j = 0; j < 4; ++j) {
      int pg = n0 + wpix0 + j * 16 + lrow;
      if (pg < 20000) {
        float4 o;
        o.x = fmaxf(acc[i][j][0] + bias.x, 0.f);
        o.y = fmaxf(acc[i][j][1] + bias.y, 0.f);
        o.z = fmaxf(acc[i][j][2] + bias.z, 0.f);
        o.w = fmaxf(acc[i][j][3] + bias.w, 0.f);
        *(float4*)&conv1[(size_t)pg * 512 + ch] = o;
      }
    }
  }
}

// ------------------------------------------------------------------
// Heads (unchanged, verified)
// ------------------------------------------------------------------
__global__ __launch_bounds__(256) void heads_kernel(
    const float* __restrict__ conv1,
    const float* __restrict__ Wreg, const float* __restrict__ breg,
    const float* __restrict__ Wcls, const float* __restrict__ bcls,
    float* __restrict__ boxes, float* __restrict__ scores) {
  __shared__ float v[4][512];
  __shared__ float o54[4][56];
  const int tid = threadIdx.x;
  const int w = tid >> 6, lane = tid & 63;
  const int pix = blockIdx.x * 4 + w;
  const int b = pix / 2500;
  const int n = pix - b * 2500;
  const int y = n / 50, x = n - y * 50;
  const float* src = conv1 + (size_t)pix * 512;
  *(float4*)&v[w][lane * 8]     = *(const float4*)&src[lane * 8];
  *(float4*)&v[w][lane * 8 + 4] = *(const float4*)&src[lane * 8 + 4];
  __syncthreads();
  if (lane < 54) {
    const float* wrow = (lane < 36) ? (Wreg + lane * 512) : (Wcls + (lane - 36) * 512);
    float s0 = 0.f, s1 = 0.f, s2 = 0.f, s3 = 0.f;
    for (int c = 0; c < 512; c += 4) {
      float4 wv = *(const float4*)&wrow[c];
      float4 vv = *(const float4*)&v[w][c];
      s0 = fmaf(vv.x, wv.x, s0);
      s1 = fmaf(vv.y, wv.y, s1);
      s2 = fmaf(vv.z, wv.z, s2);
      s3 = fmaf(vv.w, wv.w, s3);
    }
    o54[w][lane] = (s0 + s1) + (s2 + s3) + (lane < 36 ? breg[lane] : bcls[lane - 36]);
  }
  __syncthreads();
  if (lane < 9) {
    const int a = lane;
    float d0 = o54[w][a * 4 + 0], d1 = o54[w][a * 4 + 1];
    float d2 = o54[w][a * 4 + 2], d3 = o54[w][a * 4 + 3];
    float sc0 = o54[w][36 + a * 2], sc1 = o54[w][36 + a * 2 + 1];
    float mx = fmaxf(sc0, sc1);
    float e0 = expf(sc0 - mx), e1 = expf(sc1 - mx);
    float fg = e1 / (e0 + e1);
    const int ri = a / 3;
    const int si = a - ri * 3;
    float sv = (si == 0) ? 8.f : (si == 1 ? 16.f : 32.f);
    float sqr_r  = (ri == 0) ? 0.70710678f : (ri == 1 ? 1.f : 1.41421356f);
    float sqr_ir = (ri == 0) ? 1.41421356f : (ri == 1 ? 1.f : 0.70710678f);
    float hh = 16.f * sv * sqr_r;
    float ww = 16.f * sv * sqr_ir;
    float acy = 16.f * (float)(y + 1) - 25.f;
    float acx = 16.f * (float)(x + 1) - 25.f;
    float ay1 = acy - 0.5f * hh, ay2 = acy + 0.5f * hh;
    float ax1 = acx - 0.5f * ww, ax2 = acx + 0.5f * ww;
    float ah = ay2 - ay1, aw = ax2 - ax1;
    float cy0 = ay1 + 0.5f * ah, cx0 = ax1 + 0.5f * aw;
    float cy = d0 * ah + cy0, cx = d1 * aw + cx0;
    float bh = expf(d2) * ah, bw = expf(d3) * aw;
    float y1 = cy - 0.5f * bh, x1 = cx - 0.5f * bw;
    float y2 = cy + 0.5f * bh, x2 = cx + 0.5f * bw;
    y1 = fminf(fmaxf(y1, 0.f), 800.f); y2 = fminf(fmaxf(y2, 0.f), 800.f);
    x1 = fminf(fmaxf(x1, 0.f), 800.f); x2 = fminf(fmaxf(x2, 0.f), 800.f);
    bool ok = ((y2 - y1) >= 16.f) && ((x2 - x1) >= 16.f);
    int gi = b * 22500 + n * 9 + a;
    ((float4*)boxes)[gi] = make_float4(y1, x1, y2, x2);
    scores[gi] = (ok && fg == fg) ? fg : NEGV;
  }
}

// ------------------------------------------------------------------
// Top-6000 radix select (unchanged, verified)
// ------------------------------------------------------------------
__global__ __launch_bounds__(1024) void topk_kernel(
    const float* __restrict__ scores, const float* __restrict__ boxes,
    float* __restrict__ tsc, float* __restrict__ tbx, int* __restrict__ tidx) {
  const int b = blockIdx.x, tid = threadIdx.x;
  __shared__ unsigned hist[256];
  __shared__ unsigned long long sh_pref;
  __shared__ unsigned sh_rem, sh_cnt;
  const float* sc = scores + b * 22500;
  if (tid == 0) { sh_pref = 0ull; sh_rem = 6000u; }
  __syncthreads();
  for (int pass = 0; pass < 6; ++pass) {
    const int shift = 40 - pass * 8;
    if (tid < 256) hist[tid] = 0u;
    __syncthreads();
    const unsigned long long pref = sh_pref;
    for (int j = tid; j < 22500; j += 1024) {
      unsigned long long key = key48(sc[j], j);
      if ((key >> (shift + 8)) == pref)
        atomicAdd(&hist[(unsigned)(key >> shift) & 255u], 1u);
    }
    __syncthreads();
    if (tid == 0) {
      unsigned rem = sh_rem;
      unsigned c = 0; int sel = 0;
      for (int bin = 255; bin >= 0; --bin) {
        unsigned nc = c + hist[bin];
        if (nc >= rem) { sel = bin; break; }
        c = nc;
      }
      sh_rem = rem - c;
      sh_pref = (sh_pref << 8) | (unsigned long long)sel;
    }
    __syncthreads();
  }
  const unsigned long long T = sh_pref;
  if (tid == 0) sh_cnt = 0u;
  __syncthreads();
  const float4* bx4 = (const float4*)boxes;
  float4* tb4 = (float4*)tbx;
  for (int j = tid; j < 22500; j += 1024) {
    unsigned long long key = key48(sc[j], j);
    if (key >= T) {
      unsigned slot = atomicAdd(&sh_cnt, 1u);
      if (slot < 6000u) {
        tsc[b * 6000 + slot] = sc[j];
        tidx[b * 6000 + slot] = j;
        tb4[b * 6000 + slot] = bx4[b * 22500 + j];
      }
    }
  }
}

// ------------------------------------------------------------------
// Rank-sort (unchanged, verified)
// ------------------------------------------------------------------
__global__ __launch_bounds__(256) void rank_kernel(
    const float* __restrict__ tsc, const int* __restrict__ tidx,
    const float* __restrict__ tbx,
    float* __restrict__ sbx, float* __restrict__ ssc) {
  const int b = blockIdx.y;
  const int c = blockIdx.x * 256 + threadIdx.x;
  const int lane = threadIdx.x & 63;
  const float* scb = tsc + b * 6000;
  const int* idb = tidx + b * 6000;
  unsigned long long kc = (c < 6000) ? key48(scb[c], idb[c]) : 0ull;
  int rank = 0;
  for (int t = 0; t < 94; ++t) {
    int j = t * 64 + lane;
    unsigned long long kj = (j < 6000) ? key48(scb[j], idb[j]) : 0ull;
    #pragma unroll
    for (int r = 0; r < 64; ++r) {
      unsigned long long kk = __shfl(kj, r);
      rank += (kk > kc) ? 1 : 0;
    }
  }
  if (c < 6000) {
    ((float4*)sbx)[b * 6000 + rank] = ((const float4*)tbx)[b * 6000 + c];
    ssc[b * 6000 + rank] = scb[c];
  }
}

// ------------------------------------------------------------------
// Suppression bitmask (unchanged, verified)
// ------------------------------------------------------------------
__global__ __launch_bounds__(256) void mask_kernel(
    const float* __restrict__ sbx, unsigned long long* __restrict__ mask) {
  const int b = blockIdx.y;
  const int row = blockIdx.x * 64 + (threadIdx.x & 63);
  const int wseg = threadIdx.x >> 6;
  __shared__ float4 jb[512];
  const float4* sb4 = (const float4*)sbx + (size_t)b * 6000;
  float4 rb = sb4[row < 6000 ? row : 5999];
  const float ra = (rb.z - rb.x) * (rb.w - rb.y);
  unsigned long long m[24];
  #pragma unroll
  for (int q = 0; q < 24; ++q) m[q] = 0ull;
  for (int jt = 0; jt < 12; ++jt) {
    __syncthreads();
    for (int s = threadIdx.x; s < 512; s += 256) {
      int j = jt * 512 + s;
      jb[s] = (j < 6000) ? sb4[j] : make_float4(0.f, 0.f, 0.f, 0.f);
    }
    __syncthreads();
    #pragma unroll
    for (int ww = 0; ww < 2; ++ww) {
      int w = jt * 8 + wseg * 2 + ww;
      if (w >= 94) continue;
      int j0 = (wseg * 2 + ww) * 64;
      unsigned long long bits = 0ull;
      #pragma unroll
      for (int u = 0; u < 64; ++u) {
        float4 bb = jb[j0 + u];
        float aj = (bb.z - bb.x) * (bb.w - bb.y);
        float yy1 = fmaxf(rb.x, bb.x), xx1 = fmaxf(rb.y, bb.y);
        float yy2 = fminf(rb.z, bb.z), xx2 = fminf(rb.w, bb.w);
        float inter = fmaxf(yy2 - yy1, 0.f) * fmaxf(xx2 - xx1, 0.f);
        float iou = inter / (((ra + aj) - inter) + 1e-9f);
        bits |= (iou > 0.7f) ? (1ull << u) : 0ull;
      }
      m[jt * 2 + ww] = bits;
    }
  }
  if (row < 6000) {
    unsigned long long* mr = mask + (size_t)(b * 6000 + row) * 94;
    #pragma unroll
    for (int jt = 0; jt < 12; ++jt)
      #pragma unroll
      for (int ww = 0; ww < 2; ++ww) {
        int w = jt * 8 + wseg * 2 + ww;
        if (w < 94) mr[w] = m[jt * 2 + ww];
      }
  }
}

// ------------------------------------------------------------------
// Greedy bitmask walk (unchanged, verified)
// ------------------------------------------------------------------
__global__ __launch_bounds__(64) void nmsbit_kernel(
    const float* __restrict__ ssc, const float* __restrict__ sbx,
    const unsigned long long* __restrict__ mask, float* __restrict__ out) {
  const int b = blockIdx.x, lane = threadIdx.x;
  __shared__ unsigned long long live[94];
  __shared__ int picks[300];
  int cnt = 0;
  for (int j = lane; j < 6000; j += 64)
    cnt += (ssc[b * 6000 + j] > NEGH) ? 1 : 0;
  #pragma unroll
  for (int off = 32; off > 0; off >>= 1) cnt += __shfl_down(cnt, off);
  const int nvalid = __shfl(cnt, 0);
  for (int w = lane; w < 94; w += 64) {
    int base = w * 64;
    unsigned long long mm;
    if (base + 64 <= nvalid) mm = ~0ull;
    else if (base >= nvalid) mm = 0ull;
    else mm = (~0ull) >> (64 - (nvalid - base));
    live[w] = mm;
  }
  __syncthreads();
  int np = 0;
  for (int w = 0; w < 94 && np < 300; ++w) {
    unsigned long long cur = live[w];
    while (cur != 0ull && np < 300) {
      int bit = __ffsll((unsigned long long)cur) - 1;
      int i = w * 64 + bit;
      if (lane == 0) picks[np] = i;
      np++;
      const unsigned long long* mr = mask + (size_t)(b * 6000 + i) * 94;
      unsigned long long m0 = mr[lane];
      unsigned long long m1 = (lane < 30) ? mr[lane + 64] : 0ull;
      live[lane] &= ~m0;
      if (lane < 30) live[lane + 64] &= ~m1;
      __syncthreads();
      cur = live[w];
      cur &= (bit < 63) ? ((~0ull) << (bit + 1)) : 0ull;
    }
  }
  __syncthreads();
  float* rois = out;
  float* rsc  = out + 12000;
  for (int t = lane; t < 300; t += 64) {
    float* rp = rois + (size_t)(b * 300 + t) * 5;
    if (t < np) {
      int i = picks[t];
      float4 bb = ((const float4*)sbx)[b * 6000 + i];
      rp[0] = (float)b; rp[1] = bb.x; rp[2] = bb.y; rp[3] = bb.z; rp[4] = bb.w;
      rsc[b * 300 + t] = ssc[b * 6000 + i];
    } else {
      rp[0] = 0.f; rp[1] = 0.f; rp[2] = 0.f; rp[3] = 0.f; rp[4] = 0.f;
      rsc[b * 300 + t] = 0.f;
    }
  }
}

// ------------------------------------------------------------------
// fp32 conv (known-good) — small-ws fallback path only.
// ------------------------------------------------------------------
__global__ __launch_bounds__(256) void conv3x3_kernel(
    const float* __restrict__ feat, const float* __restrict__ W1,
    const float* __restrict__ b1, float* __restrict__ out) {
  __shared__ float As[36][132];
  __shared__ float Bs[36][128];
  const int tid = threadIdx.x;
  const int b  = blockIdx.z;
  const int m0 = blockIdx.y * 128;
  const int n0 = blockIdx.x * 128;
  const int tn = tid & 15, tm = tid >> 4;
  const int lm = tid & 127;
  const int kh = tid >> 7;
  const int ng = n0 + lm;
  const int yy = ng / 50;
  const int xx = ng - yy * 50;
  const bool npix_ok = (ng < 2500);
  const float* featb = feat + b * (512 * 2500);
  const float* arow  = W1 + (m0 + lm) * 4608;
  float acc[8][8];
  #pragma unroll
  for (int i = 0; i < 8; ++i)
    #pragma unroll
    for (int j = 0; j < 8; ++j) acc[i][j] = 0.f;
  for (int kc = 0; kc < 4608; kc += 36) {
    #pragma unroll
    for (int i = 0; i < 18; ++i) { int k = i * 2 + kh; As[k][lm] = arow[kc + k]; }
    #pragma unroll
    for (int i = 0; i < 18; ++i) {
      int k = i * 2 + kh;
      int kg = kc + k;
      int cin = kg / 9;
      int off = kg - cin * 9;
      int dy = off / 3;
      int dx = off - dy * 3;
      int iy = yy + dy - 1, ix = xx + dx - 1;
      float v = 0.f;
      if (npix_ok && (unsigned)iy < 50u && (unsigned)ix < 50u)
        v = featb[cin * 2500 + iy * 50 + ix];
      Bs[k][lm] = v;
    }
    __syncthreads();
    for (int k = 0; k < 36; ++k) {
      float a[8], bb[8];
      *(float4*)&a[0]  = *(const float4*)&As[k][tm * 8];
      *(float4*)&a[4]  = *(const float4*)&As[k][tm * 8 + 4];
      *(float4*)&bb[0] = *(const float4*)&Bs[k][tn * 8];
      *(float4*)&bb[4] = *(const float4*)&Bs[k][tn * 8 + 4];
      #pragma unroll
      for (int i = 0; i < 8; ++i)
        #pragma unroll
        for (int j = 0; j < 8; ++j)
          acc[i][j] = fmaf(a[i], bb[j], acc[i][j]);
    }
    __syncthreads();
  }
  float bias[8];
  *(float4*)&bias[0] = *(const float4*)&b1[m0 + tm * 8];
  *(float4*)&bias[4] = *(const float4*)&b1[m0 + tm * 8 + 4];
  for (int j = 0; j < 8; ++j) {
    int n = n0 + tn * 8 + j;
    if (n >= 2500) break;
    float* op = out + (size_t)(b * 2500 + n) * 512 + m0 + tm * 8;
    float4 v0, v1;
    v0.x = fmaxf(acc[0][j] + bias[0], 0.f); v0.y = fmaxf(acc[1][j] + bias[1], 0.f);
    v0.z = fmaxf(acc[2][j] + bias[2], 0.f); v0.w = fmaxf(acc[3][j] + bias[3], 0.f);
    v1.x = fmaxf(acc[4][j] + bias[4], 0.f); v1.y = fmaxf(acc[5][j] + bias[5], 0.f);
    v1.z = fmaxf(acc[6][j] + bias[6], 0.f); v1.w = fmaxf(acc[7][j] + bias[7], 0.f);
    *(float4*)op       = v0;
    *(float4*)(op + 4) = v1;
  }
}

// ------------------------------------------------------------------
extern "C" void kernel_launch(void* const* d_in, const int* in_sizes, int n_in,
                              void* d_out, int out_size, void* d_ws, size_t ws_size,
                              hipStream_t stream) {
  const float* feat = (const float*)d_in[0];
  const float* W1   = (const float*)d_in[1];
  const float* b1   = (const float*)d_in[2];
  const float* Wreg = (const float*)d_in[3];
  const float* breg = (const float*)d_in[4];
  const float* Wcls = (const float*)d_in[5];
  const float* bcls = (const float*)d_in[6];
  float* out = (float*)d_out;
  float* ws  = (float*)d_ws;

  const size_t NEED = 59867776ull;
  if (ws_size >= NEED) {
    unsigned* W1pack = (unsigned*)ws;
    float* conv1  = ws + 3538944;
    unsigned long long* mask = (unsigned long long*)(ws + 3538944);
    float* boxes  = ws + 13778944;
    float* sbx    = ws + 13778944;
    float* ssc    = ws + 13970944;
    float* scores = ws + 14498944;
    float* tbx    = ws + 14678944;
    float* tsc    = ws + 14870944;
    int*   tidx   = (int*)(ws + 14918944);

    w1pack_kernel<<<512, 256, 0, stream>>>(W1, W1pack);
    conv_mfma_kernel<<<dim3(79, 4), 512, 0, stream>>>(feat, (const char*)W1pack, b1, conv1);
    heads_kernel<<<5000, 256, 0, stream>>>(conv1, Wreg, breg, Wcls, bcls, boxes, scores);
    topk_kernel<<<8, 1024, 0, stream>>>(scores, boxes, tsc, tbx, tidx);
    rank_kernel<<<dim3(24, 8), 256, 0, stream>>>(tsc, tidx, tbx, sbx, ssc);
    mask_kernel<<<dim3(94, 8), 256, 0, stream>>>(sbx, mask);
    nmsbit_kernel<<<8, 64, 0, stream>>>(ssc, sbx, mask, out);
  } else if (ws_size >= 45712000ull) {
    float* conv1  = ws;
    unsigned long long* mask = (unsigned long long*)ws;
    float* boxes  = ws + 10240000;
    float* sbx    = ws + 10240000;
    float* ssc    = ws + 10432000;
    float* scores = ws + 10960000;
    float* tbx    = ws + 11140000;
    float* tsc    = ws + 11332000;
    int*   tidx   = (int*)(ws + 11380000);
    conv3x3_kernel<<<dim3(20, 4, 8), 256, 0, stream>>>(feat, W1, b1, conv1);
    heads_kernel<<<5000, 256, 0, stream>>>(conv1, Wreg, breg, Wcls, bcls, boxes, scores);
    topk_kernel<<<8, 1024, 0, stream>>>(scores, boxes, tsc, tbx, tidx);
    rank_kernel<<<dim3(24, 8), 256, 0, stream>>>(tsc, tidx, tbx, sbx, ssc);
    mask_kernel<<<dim3(94, 8), 256, 0, stream>>>(sbx, mask);
    nmsbit_kernel<<<8, 64, 0, stream>>>(ssc, sbx, mask, out);
  }
}

// Round 12
// 1726.745 us; speedup vs baseline: 1.1554x; 1.1554x over previous
//
#include <hip/hip_runtime.h>
#include <hip/hip_bf16.h>
#include <math.h>

#define NEGV -1e9f
#define NEGH -5e8f

typedef __attribute__((ext_vector_type(8))) short short8;
typedef __attribute__((ext_vector_type(4))) float f32x4;

__device__ __forceinline__ unsigned fkey(float f) {
  unsigned u = __float_as_uint(f);
  return (u & 0x80000000u) ? ~u : (u | 0x80000000u);
}
__device__ __forceinline__ unsigned long long key48(float s, int j) {
  return ((unsigned long long)fkey(s) << 15) | (unsigned long long)(32767 - j);
}
__device__ __forceinline__ unsigned short bf16_rne(float v) {
  unsigned u = __float_as_uint(v);
  unsigned r = u + 0x7FFFu + ((u >> 16) & 1u);
  return (unsigned short)(r >> 16);
}
__device__ __forceinline__ float bf16_f(unsigned short h) {
  return __uint_as_float(((unsigned)h) << 16);
}

#if defined(__has_builtin)
#if __has_builtin(__builtin_amdgcn_global_load_lds)
#define HAS_GLL 1
#endif
#endif

__device__ __forceinline__ void stage16(const char* gsrc_lane, char* ldsbase, int ln) {
#ifdef HAS_GLL
  typedef unsigned int __attribute__((address_space(1))) gu32;
  typedef unsigned int __attribute__((address_space(3))) lu32;
  __builtin_amdgcn_global_load_lds((const gu32*)gsrc_lane, (lu32*)ldsbase, 16, 0, 0);
#else
  *(uint4*)(ldsbase + ln * 16) = *(const uint4*)gsrc_lane;
#endif
}

// ==================================================================
// Tile layout (per plane: rowpairs x 128B):
//   byte(row,k) = (row>>1)*128 + ((((row&1)<<6) + 2k) ^ (((row>>1)&7)<<4))
// W1pack image order: [ct=4][s=144][plane hi/mid/lo][2048 dw]
// K-order: TAP-MAJOR (s = tap*16 + cinb) — FROZEN. The r11 cin-major
// reorder changed per-output fp accumulation order and cascaded into
// NMS pick divergence. conv1 must stay bitwise = the r5-r10 lineage.
// ==================================================================

// ------------------------------------------------------------------
// Pack W1 (coalesced, verbatim from passing round 10).
// ------------------------------------------------------------------
__global__ __launch_bounds__(256) void w1pack_kernel(
    const float* __restrict__ W1, unsigned* __restrict__ W1pack) {
  int g = blockIdx.x * 256 + threadIdx.x;   // 512*256 = 131072 exact
  int oc = g >> 8;
  int cp = g & 255;
  int cin = cp * 2;
  int ct = oc >> 7;
  int row = oc & 127;
  float buf[18];
  const float* src = W1 + (size_t)oc * 4608 + cin * 9;
  #pragma unroll
  for (int i = 0; i < 18; ++i) buf[i] = src[i];
  int k = cin & 31;
  int R = row >> 1;
  int val = ((row & 1) << 6) | (k << 1);
  int tb = (R << 7) | (val ^ ((R & 7) << 4));
  int dwimg = tb >> 2;
  int sBase = cp >> 4;                      // cin>>5
  #pragma unroll
  for (int tap = 0; tap < 9; ++tap) {
    float w0 = buf[tap], w1 = buf[9 + tap];
    unsigned short h0 = bf16_rne(w0), h1 = bf16_rne(w1);
    float r0 = w0 - bf16_f(h0), r1 = w1 - bf16_f(h1);
    unsigned short m0 = bf16_rne(r0), m1 = bf16_rne(r1);
    unsigned short l0 = bf16_rne(r0 - bf16_f(m0)), l1 = bf16_rne(r1 - bf16_f(m1));
    int s = tap * 16 + sBase;               // tap-major (frozen)
    size_t base = ((size_t)(ct * 144 + s) * 3) * 2048 + dwimg;
    W1pack[base]        = (unsigned)h0 | ((unsigned)h1 << 16);
    W1pack[base + 2048] = (unsigned)m0 | ((unsigned)m1 << 16);
    W1pack[base + 4096] = (unsigned)l0 | ((unsigned)l1 << 16);
  }
}

// ------------------------------------------------------------------
// Conv 3x3 as split-3 bf16 MFMA GEMM — verbatim round-8 kernel
// (passing, 774-818 us). conv1 bitwise = r5-r10 lineage.
// ------------------------------------------------------------------
__global__ __launch_bounds__(256) void conv_mfma_kernel(
    const float* __restrict__ feat, const char* __restrict__ W1pack,
    const float* __restrict__ b1, float* __restrict__ conv1) {
  __shared__ char smem[73728];           // A buf0 24K | A buf1 24K | B 24K
  const int tid = threadIdx.x;
  const int bid = blockIdx.x;            // 0..639
  const int xcd = bid & 7;
  const int slot = bid >> 3;             // 0..79
  const int ct = xcd >> 1;
  const int b  = ((xcd & 1) << 2) + (slot / 20);
  const int n0 = (slot % 20) * 128;
  const int wv = tid >> 6, ln = tid & 63;

  const int spix = tid & 127;
  const int kh   = tid >> 7;
  int p = n0 + spix; if (p > 2499) p = 2499;
  const int pyy = p / 50;
  const int pxx = p - pyy * 50;
  const float* featb = feat + (size_t)b * 512 * 2500;
  const char* wsrc = W1pack + (size_t)ct * 144 * 24576;

  const int wch0  = (wv >> 1) * 64;
  const int wpix0 = (wv & 1) * 64;
  const int lrow = ln & 15, lg = ln >> 4;

  f32x4 acc[4][4];
  #pragma unroll
  for (int i = 0; i < 4; ++i)
    #pragma unroll
    for (int j = 0; j < 4; ++j) acc[i][j] = (f32x4)0.f;

  float u[16];

  auto loadFeat = [&](int s) {
    int tap = s >> 4;
    int dy = tap / 3, dx = tap - dy * 3;
    int iy = pyy + dy - 1, ix = pxx + dx - 1;
    bool ok = ((unsigned)iy < 50u) && ((unsigned)ix < 50u);
    int cinb = ((s & 15) << 5) + kh * 16;
    const float* base = featb + (size_t)cinb * 2500 + iy * 50 + ix;
    #pragma unroll
    for (int i = 0; i < 16; ++i) u[i] = ok ? base[(size_t)i * 2500] : 0.f;
  };
  auto issueA = [&](int s, int buf) {
    const char* src = wsrc + (size_t)s * 24576;
    char* lbase = smem + buf * 24576 + (tid >> 6) * 1024;
    #pragma unroll
    for (int c = 0; c < 6; ++c)
      stage16(src + c * 4096 + tid * 16, lbase + c * 4096, ln);
  };
  auto writeB = [&]() {
    unsigned short h[16], m[16], l[16];
    #pragma unroll
    for (int i = 0; i < 16; ++i) {
      float v = u[i];
      h[i] = bf16_rne(v);
      float r1 = v - bf16_f(h[i]);
      m[i] = bf16_rne(r1);
      float r2 = r1 - bf16_f(m[i]);
      l[i] = bf16_rne(r2);
    }
    const int r = spix >> 1;
    const int swz = (r & 7) << 4;
    char* rowb = smem + 49152 + r * 128;
    #pragma unroll
    for (int pl = 0; pl < 3; ++pl) {
      const unsigned short* sp = (pl == 0) ? h : (pl == 1 ? m : l);
      char* pb = rowb + pl * 8192;
      #pragma unroll
      for (int q = 0; q < 4; ++q) {
        int pre = ((spix & 1) << 6) + kh * 32 + q * 8;
        uint2 w;
        w.x = (unsigned)sp[q*4]   | ((unsigned)sp[q*4+1] << 16);
        w.y = (unsigned)sp[q*4+2] | ((unsigned)sp[q*4+3] << 16);
        *(uint2*)(pb + (pre ^ swz)) = w;
      }
    }
  };
  auto rdFrag = [&](const char* base, int row) -> short8 {
    int byte = (row >> 1) * 128 +
               ((((row & 1) << 6) + (lg << 4)) ^ (((row >> 1) & 7) << 4));
    return *(const short8*)(base + byte);
  };
  auto compute = [&](int buf) {
    const char* aBase = smem + buf * 24576;
    short8 fa[3][4];
    #pragma unroll
    for (int pl = 0; pl < 3; ++pl)
      #pragma unroll
      for (int f = 0; f < 4; ++f)
        fa[pl][f] = rdFrag(aBase + pl * 8192, wch0 + f * 16 + lrow);
    #pragma unroll
    for (int jb = 0; jb < 3; ++jb) {
      short8 fb[4];
      #pragma unroll
      for (int f = 0; f < 4; ++f)
        fb[f] = rdFrag(smem + 49152 + jb * 8192, wpix0 + f * 16 + lrow);
      const int na = 3 - jb;
      #pragma unroll
      for (int ap = 0; ap < 3; ++ap) {
        if (ap < na) {
          #pragma unroll
          for (int i = 0; i < 4; ++i)
            #pragma unroll
            for (int j = 0; j < 4; ++j)
              acc[i][j] = __builtin_amdgcn_mfma_f32_16x16x32_bf16(
                  fa[ap][i], fb[j], acc[i][j], 0, 0, 0);
        }
      }
    }
  };

  loadFeat(0);
  issueA(0, 0);
  writeB();
  __syncthreads();
  issueA(1, 1);
  loadFeat(1);
  int cur = 0;
  #pragma unroll 1
  for (int s = 0; s < 144; ++s) {
    compute(cur);
    __syncthreads();
    if (s + 1 < 144) {
      writeB();
      __syncthreads();
      if (s + 2 < 144) {
        issueA(s + 2, cur);
        loadFeat(s + 2);
      }
      cur ^= 1;
    }
  }

  const int chb = ct * 128 + wch0 + lg * 4;
  #pragma unroll
  for (int i = 0; i < 4; ++i) {
    int ch = chb + i * 16;
    float4 bias = *(const float4*)&b1[ch];
    #pragma unroll
    for (int j = 0; j < 4; ++j) {
      int pix = n0 + wpix0 + j * 16 + lrow;
      if (pix < 2500) {
        float4 o;
        o.x = fmaxf(acc[i][j][0] + bias.x, 0.f);
        o.y = fmaxf(acc[i][j][1] + bias.y, 0.f);
        o.z = fmaxf(acc[i][j][2] + bias.z, 0.f);
        o.w = fmaxf(acc[i][j][3] + bias.w, 0.f);
        *(float4*)&conv1[(size_t)(b * 2500 + pix) * 512 + ch] = o;
      }
    }
  }
}

// ------------------------------------------------------------------
// Heads (unchanged, verified)
// ------------------------------------------------------------------
__global__ __launch_bounds__(256) void heads_kernel(
    const float* __restrict__ conv1,
    const float* __restrict__ Wreg, const float* __restrict__ breg,
    const float* __restrict__ Wcls, const float* __restrict__ bcls,
    float* __restrict__ boxes, float* __restrict__ scores) {
  __shared__ float v[4][512];
  __shared__ float o54[4][56];
  const int tid = threadIdx.x;
  const int w = tid >> 6, lane = tid & 63;
  const int pix = blockIdx.x * 4 + w;
  const int b = pix / 2500;
  const int n = pix - b * 2500;
  const int y = n / 50, x = n - y * 50;
  const float* src = conv1 + (size_t)pix * 512;
  *(float4*)&v[w][lane * 8]     = *(const float4*)&src[lane * 8];
  *(float4*)&v[w][lane * 8 + 4] = *(const float4*)&src[lane * 8 + 4];
  __syncthreads();
  if (lane < 54) {
    const float* wrow = (lane < 36) ? (Wreg + lane * 512) : (Wcls + (lane - 36) * 512);
    float s0 = 0.f, s1 = 0.f, s2 = 0.f, s3 = 0.f;
    for (int c = 0; c < 512; c += 4) {
      float4 wv = *(const float4*)&wrow[c];
      float4 vv = *(const float4*)&v[w][c];
      s0 = fmaf(vv.x, wv.x, s0);
      s1 = fmaf(vv.y, wv.y, s1);
      s2 = fmaf(vv.z, wv.z, s2);
      s3 = fmaf(vv.w, wv.w, s3);
    }
    o54[w][lane] = (s0 + s1) + (s2 + s3) + (lane < 36 ? breg[lane] : bcls[lane - 36]);
  }
  __syncthreads();
  if (lane < 9) {
    const int a = lane;
    float d0 = o54[w][a * 4 + 0], d1 = o54[w][a * 4 + 1];
    float d2 = o54[w][a * 4 + 2], d3 = o54[w][a * 4 + 3];
    float sc0 = o54[w][36 + a * 2], sc1 = o54[w][36 + a * 2 + 1];
    float mx = fmaxf(sc0, sc1);
    float e0 = expf(sc0 - mx), e1 = expf(sc1 - mx);
    float fg = e1 / (e0 + e1);
    const int ri = a / 3;
    const int si = a - ri * 3;
    float sv = (si == 0) ? 8.f : (si == 1 ? 16.f : 32.f);
    float sqr_r  = (ri == 0) ? 0.70710678f : (ri == 1 ? 1.f : 1.41421356f);
    float sqr_ir = (ri == 0) ? 1.41421356f : (ri == 1 ? 1.f : 0.70710678f);
    float hh = 16.f * sv * sqr_r;
    float ww = 16.f * sv * sqr_ir;
    float acy = 16.f * (float)(y + 1) - 25.f;
    float acx = 16.f * (float)(x + 1) - 25.f;
    float ay1 = acy - 0.5f * hh, ay2 = acy + 0.5f * hh;
    float ax1 = acx - 0.5f * ww, ax2 = acx + 0.5f * ww;
    float ah = ay2 - ay1, aw = ax2 - ax1;
    float cy0 = ay1 + 0.5f * ah, cx0 = ax1 + 0.5f * aw;
    float cy = d0 * ah + cy0, cx = d1 * aw + cx0;
    float bh = expf(d2) * ah, bw = expf(d3) * aw;
    float y1 = cy - 0.5f * bh, x1 = cx - 0.5f * bw;
    float y2 = cy + 0.5f * bh, x2 = cx + 0.5f * bw;
    y1 = fminf(fmaxf(y1, 0.f), 800.f); y2 = fminf(fmaxf(y2, 0.f), 800.f);
    x1 = fminf(fmaxf(x1, 0.f), 800.f); x2 = fminf(fmaxf(x2, 0.f), 800.f);
    bool ok = ((y2 - y1) >= 16.f) && ((x2 - x1) >= 16.f);
    int gi = b * 22500 + n * 9 + a;
    ((float4*)boxes)[gi] = make_float4(y1, x1, y2, x2);
    scores[gi] = (ok && fg == fg) ? fg : NEGV;
  }
}

// ------------------------------------------------------------------
// Top-6000 radix select (unchanged, verified)
// ------------------------------------------------------------------
__global__ __launch_bounds__(1024) void topk_kernel(
    const float* __restrict__ scores, const float* __restrict__ boxes,
    float* __restrict__ tsc, float* __restrict__ tbx, int* __restrict__ tidx) {
  const int b = blockIdx.x, tid = threadIdx.x;
  __shared__ unsigned hist[256];
  __shared__ unsigned long long sh_pref;
  __shared__ unsigned sh_rem, sh_cnt;
  const float* sc = scores + b * 22500;
  if (tid == 0) { sh_pref = 0ull; sh_rem = 6000u; }
  __syncthreads();
  for (int pass = 0; pass < 6; ++pass) {
    const int shift = 40 - pass * 8;
    if (tid < 256) hist[tid] = 0u;
    __syncthreads();
    const unsigned long long pref = sh_pref;
    for (int j = tid; j < 22500; j += 1024) {
      unsigned long long key = key48(sc[j], j);
      if ((key >> (shift + 8)) == pref)
        atomicAdd(&hist[(unsigned)(key >> shift) & 255u], 1u);
    }
    __syncthreads();
    if (tid == 0) {
      unsigned rem = sh_rem;
      unsigned c = 0; int sel = 0;
      for (int bin = 255; bin >= 0; --bin) {
        unsigned nc = c + hist[bin];
        if (nc >= rem) { sel = bin; break; }
        c = nc;
      }
      sh_rem = rem - c;
      sh_pref = (sh_pref << 8) | (unsigned long long)sel;
    }
    __syncthreads();
  }
  const unsigned long long T = sh_pref;
  if (tid == 0) sh_cnt = 0u;
  __syncthreads();
  const float4* bx4 = (const float4*)boxes;
  float4* tb4 = (float4*)tbx;
  for (int j = tid; j < 22500; j += 1024) {
    unsigned long long key = key48(sc[j], j);
    if (key >= T) {
      unsigned slot = atomicAdd(&sh_cnt, 1u);
      if (slot < 6000u) {
        tsc[b * 6000 + slot] = sc[j];
        tidx[b * 6000 + slot] = j;
        tb4[b * 6000 + slot] = bx4[b * 22500 + j];
      }
    }
  }
}

// ------------------------------------------------------------------
// Rank-sort (unchanged, verified)
// ------------------------------------------------------------------
__global__ __launch_bounds__(256) void rank_kernel(
    const float* __restrict__ tsc, const int* __restrict__ tidx,
    const float* __restrict__ tbx,
    float* __restrict__ sbx, float* __restrict__ ssc) {
  const int b = blockIdx.y;
  const int c = blockIdx.x * 256 + threadIdx.x;
  const int lane = threadIdx.x & 63;
  const float* scb = tsc + b * 6000;
  const int* idb = tidx + b * 6000;
  unsigned long long kc = (c < 6000) ? key48(scb[c], idb[c]) : 0ull;
  int rank = 0;
  for (int t = 0; t < 94; ++t) {
    int j = t * 64 + lane;
    unsigned long long kj = (j < 6000) ? key48(scb[j], idb[j]) : 0ull;
    #pragma unroll
    for (int r = 0; r < 64; ++r) {
      unsigned long long kk = __shfl(kj, r);
      rank += (kk > kc) ? 1 : 0;
    }
  }
  if (c < 6000) {
    ((float4*)sbx)[b * 6000 + rank] = ((const float4*)tbx)[b * 6000 + c];
    ssc[b * 6000 + rank] = scb[c];
  }
}

// ------------------------------------------------------------------
// Suppression bitmask (unchanged, verified)
// ------------------------------------------------------------------
__global__ __launch_bounds__(256) void mask_kernel(
    const float* __restrict__ sbx, unsigned long long* __restrict__ mask) {
  const int b = blockIdx.y;
  const int row = blockIdx.x * 64 + (threadIdx.x & 63);
  const int wseg = threadIdx.x >> 6;
  __shared__ float4 jb[512];
  const float4* sb4 = (const float4*)sbx + (size_t)b * 6000;
  float4 rb = sb4[row < 6000 ? row : 5999];
  const float ra = (rb.z - rb.x) * (rb.w - rb.y);
  unsigned long long m[24];
  #pragma unroll
  for (int q = 0; q < 24; ++q) m[q] = 0ull;
  for (int jt = 0; jt < 12; ++jt) {
    __syncthreads();
    for (int s = threadIdx.x; s < 512; s += 256) {
      int j = jt * 512 + s;
      jb[s] = (j < 6000) ? sb4[j] : make_float4(0.f, 0.f, 0.f, 0.f);
    }
    __syncthreads();
    #pragma unroll
    for (int ww = 0; ww < 2; ++ww) {
      int w = jt * 8 + wseg * 2 + ww;
      if (w >= 94) continue;
      int j0 = (wseg * 2 + ww) * 64;
      unsigned long long bits = 0ull;
      #pragma unroll
      for (int u = 0; u < 64; ++u) {
        float4 bb = jb[j0 + u];
        float aj = (bb.z - bb.x) * (bb.w - bb.y);
        float yy1 = fmaxf(rb.x, bb.x), xx1 = fmaxf(rb.y, bb.y);
        float yy2 = fminf(rb.z, bb.z), xx2 = fminf(rb.w, bb.w);
        float inter = fmaxf(yy2 - yy1, 0.f) * fmaxf(xx2 - xx1, 0.f);
        float iou = inter / (((ra + aj) - inter) + 1e-9f);
        bits |= (iou > 0.7f) ? (1ull << u) : 0ull;
      }
      m[jt * 2 + ww] = bits;
    }
  }
  if (row < 6000) {
    unsigned long long* mr = mask + (size_t)(b * 6000 + row) * 94;
    #pragma unroll
    for (int jt = 0; jt < 12; ++jt)
      #pragma unroll
      for (int ww = 0; ww < 2; ++ww) {
        int w = jt * 8 + wseg * 2 + ww;
        if (w < 94) mr[w] = m[jt * 2 + ww];
      }
  }
}

// ------------------------------------------------------------------
// Greedy bitmask walk v2: CHUNKED. Same pick sequence provably:
// earlier-chunk suppression lands in live[] before a chunk is
// processed; in-chunk suppression uses the diagonal mask word.
// Serial HBM latencies: ~2 per non-empty chunk (vs 1 per pick).
// ------------------------------------------------------------------
__global__ __launch_bounds__(64) void nmsbit_kernel(
    const float* __restrict__ ssc, const float* __restrict__ sbx,
    const unsigned long long* __restrict__ mask, float* __restrict__ out) {
  const int b = blockIdx.x, lane = threadIdx.x;
  __shared__ unsigned long long live[94];
  __shared__ int picks[300];
  int cnt = 0;
  for (int j = lane; j < 6000; j += 64)
    cnt += (ssc[b * 6000 + j] > NEGH) ? 1 : 0;
  #pragma unroll
  for (int off = 32; off > 0; off >>= 1) cnt += __shfl_down(cnt, off);
  const int nvalid = __shfl(cnt, 0);
  for (int w = lane; w < 94; w += 64) {
    int base = w * 64;
    unsigned long long mm;
    if (base + 64 <= nvalid) mm = ~0ull;
    else if (base >= nvalid) mm = 0ull;
    else mm = (~0ull) >> (64 - (nvalid - base));
    live[w] = mm;
  }
  __syncthreads();

  int np = 0;
  for (int c = 0; c < 94 && np < 300; ++c) {
    unsigned long long bits = live[c];
    if (bits == 0ull) continue;
    // one parallel burst: diagonal word of every row in this chunk
    int row = c * 64 + lane;
    unsigned long long dw = (row < 6000)
        ? mask[(size_t)(b * 6000 + row) * 94 + c] : 0ull;
    // in-register uniform greedy within the chunk (no memory access)
    unsigned long long prows = 0ull;
    while (bits != 0ull && np < 300) {
      int bpos = __ffsll(bits) - 1;
      if (lane == 0) picks[np] = c * 64 + bpos;
      np++;
      prows |= (1ull << bpos);
      unsigned long long dwb = __shfl(dw, bpos);
      bits &= ~dwb;
      bits &= ~(1ull << bpos);   // guarantee progress (self-bit)
    }
    // one parallel burst: apply full rows of this chunk's picks
    unsigned long long acc0 = 0ull, acc1 = 0ull;
    unsigned long long pr = prows;
    while (pr != 0ull) {
      int bpos = __ffsll(pr) - 1; pr &= pr - 1ull;
      const unsigned long long* mr = mask + (size_t)(b * 6000 + c * 64 + bpos) * 94;
      acc0 |= mr[lane];
      if (lane < 30) acc1 |= mr[lane + 64];
    }
    if (prows != 0ull) {
      live[lane] &= ~acc0;
      if (lane < 30) live[lane + 64] &= ~acc1;
      __syncthreads();
    }
  }
  __syncthreads();

  float* rois = out;
  float* rsc  = out + 12000;
  for (int t = lane; t < 300; t += 64) {
    float* rp = rois + (size_t)(b * 300 + t) * 5;
    if (t < np) {
      int i = picks[t];
      float4 bb = ((const float4*)sbx)[b * 6000 + i];
      rp[0] = (float)b; rp[1] = bb.x; rp[2] = bb.y; rp[3] = bb.z; rp[4] = bb.w;
      rsc[b * 300 + t] = ssc[b * 6000 + i];
    } else {
      rp[0] = 0.f; rp[1] = 0.f; rp[2] = 0.f; rp[3] = 0.f; rp[4] = 0.f;
      rsc[b * 300 + t] = 0.f;
    }
  }
}

// ------------------------------------------------------------------
// fp32 conv (known-good) — small-ws fallback path only.
// ------------------------------------------------------------------
__global__ __launch_bounds__(256) void conv3x3_kernel(
    const float* __restrict__ feat, const float* __restrict__ W1,
    const float* __restrict__ b1, float* __restrict__ out) {
  __shared__ float As[36][132];
  __shared__ float Bs[36][128];
  const int tid = threadIdx.x;
  const int b  = blockIdx.z;
  const int m0 = blockIdx.y * 128;
  const int n0 = blockIdx.x * 128;
  const int tn = tid & 15, tm = tid >> 4;
  const int lm = tid & 127;
  const int kh = tid >> 7;
  const int ng = n0 + lm;
  const int yy = ng / 50;
  const int xx = ng - yy * 50;
  const bool npix_ok = (ng < 2500);
  const float* featb = feat + b * (512 * 2500);
  const float* arow  = W1 + (m0 + lm) * 4608;
  float acc[8][8];
  #pragma unroll
  for (int i = 0; i < 8; ++i)
    #pragma unroll
    for (int j = 0; j < 8; ++j) acc[i][j] = 0.f;
  for (int kc = 0; kc < 4608; kc += 36) {
    #pragma unroll
    for (int i = 0; i < 18; ++i) { int k = i * 2 + kh; As[k][lm] = arow[kc + k]; }
    #pragma unroll
    for (int i = 0; i < 18; ++i) {
      int k = i * 2 + kh;
      int kg = kc + k;
      int cin = kg / 9;
      int off = kg - cin * 9;
      int dy = off / 3;
      int dx = off - dy * 3;
      int iy = yy + dy - 1, ix = xx + dx - 1;
      float v = 0.f;
      if (npix_ok && (unsigned)iy < 50u && (unsigned)ix < 50u)
        v = featb[cin * 2500 + iy * 50 + ix];
      Bs[k][lm] = v;
    }
    __syncthreads();
    for (int k = 0; k < 36; ++k) {
      float a[8], bb[8];
      *(float4*)&a[0]  = *(const float4*)&As[k][tm * 8];
      *(float4*)&a[4]  = *(const float4*)&As[k][tm * 8 + 4];
      *(float4*)&bb[0] = *(const float4*)&Bs[k][tn * 8];
      *(float4*)&bb[4] = *(const float4*)&Bs[k][tn * 8 + 4];
      #pragma unroll
      for (int i = 0; i < 8; ++i)
        #pragma unroll
        for (int j = 0; j < 8; ++j)
          acc[i][j] = fmaf(a[i], bb[j], acc[i][j]);
    }
    __syncthreads();
  }
  float bias[8];
  *(float4*)&bias[0] = *(const float4*)&b1[m0 + tm * 8];
  *(float4*)&bias[4] = *(const float4*)&b1[m0 + tm * 8 + 4];
  for (int j = 0; j < 8; ++j) {
    int n = n0 + tn * 8 + j;
    if (n >= 2500) break;
    float* op = out + (size_t)(b * 2500 + n) * 512 + m0 + tm * 8;
    float4 v0, v1;
    v0.x = fmaxf(acc[0][j] + bias[0], 0.f); v0.y = fmaxf(acc[1][j] + bias[1], 0.f);
    v0.z = fmaxf(acc[2][j] + bias[2], 0.f); v0.w = fmaxf(acc[3][j] + bias[3], 0.f);
    v1.x = fmaxf(acc[4][j] + bias[4], 0.f); v1.y = fmaxf(acc[5][j] + bias[5], 0.f);
    v1.z = fmaxf(acc[6][j] + bias[6], 0.f); v1.w = fmaxf(acc[7][j] + bias[7], 0.f);
    *(float4*)op       = v0;
    *(float4*)(op + 4) = v1;
  }
}

// ------------------------------------------------------------------
extern "C" void kernel_launch(void* const* d_in, const int* in_sizes, int n_in,
                              void* d_out, int out_size, void* d_ws, size_t ws_size,
                              hipStream_t stream) {
  const float* feat = (const float*)d_in[0];
  const float* W1   = (const float*)d_in[1];
  const float* b1   = (const float*)d_in[2];
  const float* Wreg = (const float*)d_in[3];
  const float* breg = (const float*)d_in[4];
  const float* Wcls = (const float*)d_in[5];
  const float* bcls = (const float*)d_in[6];
  float* out = (float*)d_out;
  float* ws  = (float*)d_ws;

  const size_t NEED = 59867776ull;
  if (ws_size >= NEED) {
    unsigned* W1pack = (unsigned*)ws;
    float* conv1  = ws + 3538944;
    unsigned long long* mask = (unsigned long long*)(ws + 3538944);
    float* boxes  = ws + 13778944;
    float* sbx    = ws + 13778944;
    float* ssc    = ws + 13970944;
    float* scores = ws + 14498944;
    float* tbx    = ws + 14678944;
    float* tsc    = ws + 14870944;
    int*   tidx   = (int*)(ws + 14918944);

    w1pack_kernel<<<512, 256, 0, stream>>>(W1, W1pack);
    conv_mfma_kernel<<<640, 256, 0, stream>>>(feat, (const char*)W1pack, b1, conv1);
    heads_kernel<<<5000, 256, 0, stream>>>(conv1, Wreg, breg, Wcls, bcls, boxes, scores);
    topk_kernel<<<8, 1024, 0, stream>>>(scores, boxes, tsc, tbx, tidx);
    rank_kernel<<<dim3(24, 8), 256, 0, stream>>>(tsc, tidx, tbx, sbx, ssc);
    mask_kernel<<<dim3(94, 8), 256, 0, stream>>>(sbx, mask);
    nmsbit_kernel<<<8, 64, 0, stream>>>(ssc, sbx, mask, out);
  } else if (ws_size >= 45712000ull) {
    float* conv1  = ws;
    unsigned long long* mask = (unsigned long long*)ws;
    float* boxes  = ws + 10240000;
    float* sbx    = ws + 10240000;
    float* ssc    = ws + 10432000;
    float* scores = ws + 10960000;
    float* tbx    = ws + 11140000;
    float* tsc    = ws + 11332000;
    int*   tidx   = (int*)(ws + 11380000);
    conv3x3_kernel<<<dim3(20, 4, 8), 256, 0, stream>>>(feat, W1, b1, conv1);
    heads_kernel<<<5000, 256, 0, stream>>>(conv1, Wreg, breg, Wcls, bcls, boxes, scores);
    topk_kernel<<<8, 1024, 0, stream>>>(scores, boxes, tsc, tbx, tidx);
    rank_kernel<<<dim3(24, 8), 256, 0, stream>>>(tsc, tidx, tbx, sbx, ssc);
    mask_kernel<<<dim3(94, 8), 256, 0, stream>>>(sbx, mask);
    nmsbit_kernel<<<8, 64, 0, stream>>>(ssc, sbx, mask, out);
  }
}

// Round 13
// 1509.201 us; speedup vs baseline: 1.3220x; 1.1441x over previous
//
#include <hip/hip_runtime.h>
#include <hip/hip_bf16.h>
#include <math.h>

#define NEGV -1e9f
#define NEGH -5e8f

typedef __attribute__((ext_vector_type(8))) short short8;
typedef __attribute__((ext_vector_type(4))) float f32x4;

__device__ __forceinline__ unsigned fkey(float f) {
  unsigned u = __float_as_uint(f);
  return (u & 0x80000000u) ? ~u : (u | 0x80000000u);
}
__device__ __forceinline__ unsigned long long key48(float s, int j) {
  return ((unsigned long long)fkey(s) << 15) | (unsigned long long)(32767 - j);
}
__device__ __forceinline__ unsigned short bf16_rne(float v) {
  unsigned u = __float_as_uint(v);
  unsigned r = u + 0x7FFFu + ((u >> 16) & 1u);
  return (unsigned short)(r >> 16);
}
__device__ __forceinline__ float bf16_f(unsigned short h) {
  return __uint_as_float(((unsigned)h) << 16);
}

#if defined(__has_builtin)
#if __has_builtin(__builtin_amdgcn_global_load_lds)
#define HAS_GLL 1
#endif
#endif

__device__ __forceinline__ void stage16(const char* gsrc_lane, char* ldsbase, int ln) {
#ifdef HAS_GLL
  typedef unsigned int __attribute__((address_space(1))) gu32;
  typedef unsigned int __attribute__((address_space(3))) lu32;
  __builtin_amdgcn_global_load_lds((const gu32*)gsrc_lane, (lu32*)ldsbase, 16, 0, 0);
#else
  *(uint4*)(ldsbase + ln * 16) = *(const uint4*)gsrc_lane;
#endif
}

// ==================================================================
// Tile layout (per plane: rowpairs x 128B):
//   byte(row,k) = (row>>1)*128 + ((((row&1)<<6) + 2k) ^ (((row>>1)&7)<<4))
// W1pack image order: [ct=4][s=144][plane hi/mid/lo][2048 dw]
// K-order: TAP-MAJOR — FROZEN (r11: any accumulation-order change
// cascades through NMS ties into absmax 800).
// ==================================================================

// ------------------------------------------------------------------
// Pack W1 (coalesced, verbatim from passing rounds 10/12).
// ------------------------------------------------------------------
__global__ __launch_bounds__(256) void w1pack_kernel(
    const float* __restrict__ W1, unsigned* __restrict__ W1pack) {
  int g = blockIdx.x * 256 + threadIdx.x;   // 512*256 = 131072 exact
  int oc = g >> 8;
  int cp = g & 255;
  int cin = cp * 2;
  int ct = oc >> 7;
  int row = oc & 127;
  float buf[18];
  const float* src = W1 + (size_t)oc * 4608 + cin * 9;
  #pragma unroll
  for (int i = 0; i < 18; ++i) buf[i] = src[i];
  int k = cin & 31;
  int R = row >> 1;
  int val = ((row & 1) << 6) | (k << 1);
  int tb = (R << 7) | (val ^ ((R & 7) << 4));
  int dwimg = tb >> 2;
  int sBase = cp >> 4;                      // cin>>5
  #pragma unroll
  for (int tap = 0; tap < 9; ++tap) {
    float w0 = buf[tap], w1 = buf[9 + tap];
    unsigned short h0 = bf16_rne(w0), h1 = bf16_rne(w1);
    float r0 = w0 - bf16_f(h0), r1 = w1 - bf16_f(h1);
    unsigned short m0 = bf16_rne(r0), m1 = bf16_rne(r1);
    unsigned short l0 = bf16_rne(r0 - bf16_f(m0)), l1 = bf16_rne(r1 - bf16_f(m1));
    int s = tap * 16 + sBase;               // tap-major (frozen)
    size_t base = ((size_t)(ct * 144 + s) * 3) * 2048 + dwimg;
    W1pack[base]        = (unsigned)h0 | ((unsigned)h1 << 16);
    W1pack[base + 2048] = (unsigned)m0 | ((unsigned)m1 << 16);
    W1pack[base + 4096] = (unsigned)l0 | ((unsigned)l1 << 16);
  }
}

// ------------------------------------------------------------------
// Heads weight transpose: Wt[c*54+j] = W{reg,cls} row j, channel c.
// ------------------------------------------------------------------
__global__ __launch_bounds__(256) void wtpack_kernel(
    const float* __restrict__ Wreg, const float* __restrict__ Wcls,
    float* __restrict__ Wt) {
  int i = blockIdx.x * 256 + threadIdx.x;   // 108*256 = 27648 exact
  int c = i / 54, j = i - c * 54;
  Wt[i] = (j < 36) ? Wreg[j * 512 + c] : Wcls[(j - 36) * 512 + c];
}

// ------------------------------------------------------------------
// Conv 3x3 as split-3 bf16 MFMA GEMM — verbatim round-8/12 kernel.
// conv1 bitwise = r5-r12 lineage.
// ------------------------------------------------------------------
__global__ __launch_bounds__(256) void conv_mfma_kernel(
    const float* __restrict__ feat, const char* __restrict__ W1pack,
    const float* __restrict__ b1, float* __restrict__ conv1) {
  __shared__ char smem[73728];           // A buf0 24K | A buf1 24K | B 24K
  const int tid = threadIdx.x;
  const int bid = blockIdx.x;            // 0..639
  const int xcd = bid & 7;
  const int slot = bid >> 3;             // 0..79
  const int ct = xcd >> 1;
  const int b  = ((xcd & 1) << 2) + (slot / 20);
  const int n0 = (slot % 20) * 128;
  const int wv = tid >> 6, ln = tid & 63;

  const int spix = tid & 127;
  const int kh   = tid >> 7;
  int p = n0 + spix; if (p > 2499) p = 2499;
  const int pyy = p / 50;
  const int pxx = p - pyy * 50;
  const float* featb = feat + (size_t)b * 512 * 2500;
  const char* wsrc = W1pack + (size_t)ct * 144 * 24576;

  const int wch0  = (wv >> 1) * 64;
  const int wpix0 = (wv & 1) * 64;
  const int lrow = ln & 15, lg = ln >> 4;

  f32x4 acc[4][4];
  #pragma unroll
  for (int i = 0; i < 4; ++i)
    #pragma unroll
    for (int j = 0; j < 4; ++j) acc[i][j] = (f32x4)0.f;

  float u[16];

  auto loadFeat = [&](int s) {
    int tap = s >> 4;
    int dy = tap / 3, dx = tap - dy * 3;
    int iy = pyy + dy - 1, ix = pxx + dx - 1;
    bool ok = ((unsigned)iy < 50u) && ((unsigned)ix < 50u);
    int cinb = ((s & 15) << 5) + kh * 16;
    const float* base = featb + (size_t)cinb * 2500 + iy * 50 + ix;
    #pragma unroll
    for (int i = 0; i < 16; ++i) u[i] = ok ? base[(size_t)i * 2500] : 0.f;
  };
  auto issueA = [&](int s, int buf) {
    const char* src = wsrc + (size_t)s * 24576;
    char* lbase = smem + buf * 24576 + (tid >> 6) * 1024;
    #pragma unroll
    for (int c = 0; c < 6; ++c)
      stage16(src + c * 4096 + tid * 16, lbase + c * 4096, ln);
  };
  auto writeB = [&]() {
    unsigned short h[16], m[16], l[16];
    #pragma unroll
    for (int i = 0; i < 16; ++i) {
      float v = u[i];
      h[i] = bf16_rne(v);
      float r1 = v - bf16_f(h[i]);
      m[i] = bf16_rne(r1);
      float r2 = r1 - bf16_f(m[i]);
      l[i] = bf16_rne(r2);
    }
    const int r = spix >> 1;
    const int swz = (r & 7) << 4;
    char* rowb = smem + 49152 + r * 128;
    #pragma unroll
    for (int pl = 0; pl < 3; ++pl) {
      const unsigned short* sp = (pl == 0) ? h : (pl == 1 ? m : l);
      char* pb = rowb + pl * 8192;
      #pragma unroll
      for (int q = 0; q < 4; ++q) {
        int pre = ((spix & 1) << 6) + kh * 32 + q * 8;
        uint2 w;
        w.x = (unsigned)sp[q*4]   | ((unsigned)sp[q*4+1] << 16);
        w.y = (unsigned)sp[q*4+2] | ((unsigned)sp[q*4+3] << 16);
        *(uint2*)(pb + (pre ^ swz)) = w;
      }
    }
  };
  auto rdFrag = [&](const char* base, int row) -> short8 {
    int byte = (row >> 1) * 128 +
               ((((row & 1) << 6) + (lg << 4)) ^ (((row >> 1) & 7) << 4));
    return *(const short8*)(base + byte);
  };
  auto compute = [&](int buf) {
    const char* aBase = smem + buf * 24576;
    short8 fa[3][4];
    #pragma unroll
    for (int pl = 0; pl < 3; ++pl)
      #pragma unroll
      for (int f = 0; f < 4; ++f)
        fa[pl][f] = rdFrag(aBase + pl * 8192, wch0 + f * 16 + lrow);
    #pragma unroll
    for (int jb = 0; jb < 3; ++jb) {
      short8 fb[4];
      #pragma unroll
      for (int f = 0; f < 4; ++f)
        fb[f] = rdFrag(smem + 49152 + jb * 8192, wpix0 + f * 16 + lrow);
      const int na = 3 - jb;
      #pragma unroll
      for (int ap = 0; ap < 3; ++ap) {
        if (ap < na) {
          #pragma unroll
          for (int i = 0; i < 4; ++i)
            #pragma unroll
            for (int j = 0; j < 4; ++j)
              acc[i][j] = __builtin_amdgcn_mfma_f32_16x16x32_bf16(
                  fa[ap][i], fb[j], acc[i][j], 0, 0, 0);
        }
      }
    }
  };

  loadFeat(0);
  issueA(0, 0);
  writeB();
  __syncthreads();
  issueA(1, 1);
  loadFeat(1);
  int cur = 0;
  #pragma unroll 1
  for (int s = 0; s < 144; ++s) {
    compute(cur);
    __syncthreads();
    if (s + 1 < 144) {
      writeB();
      __syncthreads();
      if (s + 2 < 144) {
        issueA(s + 2, cur);
        loadFeat(s + 2);
      }
      cur ^= 1;
    }
  }

  const int chb = ct * 128 + wch0 + lg * 4;
  #pragma unroll
  for (int i = 0; i < 4; ++i) {
    int ch = chb + i * 16;
    float4 bias = *(const float4*)&b1[ch];
    #pragma unroll
    for (int j = 0; j < 4; ++j) {
      int pix = n0 + wpix0 + j * 16 + lrow;
      if (pix < 2500) {
        float4 o;
        o.x = fmaxf(acc[i][j][0] + bias.x, 0.f);
        o.y = fmaxf(acc[i][j][1] + bias.y, 0.f);
        o.z = fmaxf(acc[i][j][2] + bias.z, 0.f);
        o.w = fmaxf(acc[i][j][3] + bias.w, 0.f);
        *(float4*)&conv1[(size_t)(b * 2500 + pix) * 512 + ch] = o;
      }
    }
  }
}

// ------------------------------------------------------------------
// Heads v2: 16 pixels/block (4/wave), transposed coalesced weights.
// fp ops per (pixel,row) BITWISE IDENTICAL to the verified heads:
// same s0..s3 split over the same c order, same combine, same decode.
// ------------------------------------------------------------------
__global__ __launch_bounds__(256) void heads_kernel(
    const float* __restrict__ conv1, const float* __restrict__ Wt,
    const float* __restrict__ breg, const float* __restrict__ bcls,
    float* __restrict__ boxes, float* __restrict__ scores) {
  __shared__ float v[16][512];
  __shared__ float o54[16][56];
  const int tid = threadIdx.x;
  const int wvi = tid >> 6, lane = tid & 63;
  const int pix0 = blockIdx.x * 16;       // 1250 blocks, 20000 exact
  // coalesced stage: block's conv1 region is 32KB contiguous
  float4* vf = (float4*)v;
  const float4* src4 = (const float4*)(conv1 + (size_t)pix0 * 512);
  #pragma unroll
  for (int i = 0; i < 8; ++i) vf[i * 256 + tid] = src4[i * 256 + tid];
  __syncthreads();

  if (lane < 54) {
    float s[4][4];
    #pragma unroll
    for (int p = 0; p < 4; ++p)
      #pragma unroll
      for (int q = 0; q < 4; ++q) s[p][q] = 0.f;
    const int pl0 = wvi * 4;
    for (int c = 0; c < 512; c += 4) {
      float w0 = Wt[(c + 0) * 54 + lane];
      float w1 = Wt[(c + 1) * 54 + lane];
      float w2 = Wt[(c + 2) * 54 + lane];
      float w3 = Wt[(c + 3) * 54 + lane];
      #pragma unroll
      for (int p = 0; p < 4; ++p) {
        s[p][0] = fmaf(v[pl0 + p][c],     w0, s[p][0]);
        s[p][1] = fmaf(v[pl0 + p][c + 1], w1, s[p][1]);
        s[p][2] = fmaf(v[pl0 + p][c + 2], w2, s[p][2]);
        s[p][3] = fmaf(v[pl0 + p][c + 3], w3, s[p][3]);
      }
    }
    float bias = (lane < 36) ? breg[lane] : bcls[lane - 36];
    #pragma unroll
    for (int p = 0; p < 4; ++p)
      o54[pl0 + p][lane] = (s[p][0] + s[p][1]) + (s[p][2] + s[p][3]) + bias;
  }
  __syncthreads();

  if (tid < 144) {                        // 16 pixels x 9 anchors
    const int pl = tid / 9;
    const int a  = tid - pl * 9;
    const int pix = pix0 + pl;
    const int b = pix / 2500;
    const int n = pix - b * 2500;
    const int y = n / 50, x = n - y * 50;
    float d0 = o54[pl][a * 4 + 0], d1 = o54[pl][a * 4 + 1];
    float d2 = o54[pl][a * 4 + 2], d3 = o54[pl][a * 4 + 3];
    float sc0 = o54[pl][36 + a * 2], sc1 = o54[pl][36 + a * 2 + 1];
    float mx = fmaxf(sc0, sc1);
    float e0 = expf(sc0 - mx), e1 = expf(sc1 - mx);
    float fg = e1 / (e0 + e1);
    const int ri = a / 3;
    const int si = a - ri * 3;
    float sv = (si == 0) ? 8.f : (si == 1 ? 16.f : 32.f);
    float sqr_r  = (ri == 0) ? 0.70710678f : (ri == 1 ? 1.f : 1.41421356f);
    float sqr_ir = (ri == 0) ? 1.41421356f : (ri == 1 ? 1.f : 0.70710678f);
    float hh = 16.f * sv * sqr_r;
    float ww = 16.f * sv * sqr_ir;
    float acy = 16.f * (float)(y + 1) - 25.f;
    float acx = 16.f * (float)(x + 1) - 25.f;
    float ay1 = acy - 0.5f * hh, ay2 = acy + 0.5f * hh;
    float ax1 = acx - 0.5f * ww, ax2 = acx + 0.5f * ww;
    float ah = ay2 - ay1, aw = ax2 - ax1;
    float cy0 = ay1 + 0.5f * ah, cx0 = ax1 + 0.5f * aw;
    float cy = d0 * ah + cy0, cx = d1 * aw + cx0;
    float bh = expf(d2) * ah, bw = expf(d3) * aw;
    float y1 = cy - 0.5f * bh, x1 = cx - 0.5f * bw;
    float y2 = cy + 0.5f * bh, x2 = cx + 0.5f * bw;
    y1 = fminf(fmaxf(y1, 0.f), 800.f); y2 = fminf(fmaxf(y2, 0.f), 800.f);
    x1 = fminf(fmaxf(x1, 0.f), 800.f); x2 = fminf(fmaxf(x2, 0.f), 800.f);
    bool ok = ((y2 - y1) >= 16.f) && ((x2 - x1) >= 16.f);
    int gi = b * 22500 + n * 9 + a;
    ((float4*)boxes)[gi] = make_float4(y1, x1, y2, x2);
    scores[gi] = (ok && fg == fg) ? fg : NEGV;
  }
}

// ------------------------------------------------------------------
// Top-6000 radix select (unchanged, verified)
// ------------------------------------------------------------------
__global__ __launch_bounds__(1024) void topk_kernel(
    const float* __restrict__ scores, const float* __restrict__ boxes,
    float* __restrict__ tsc, float* __restrict__ tbx, int* __restrict__ tidx) {
  const int b = blockIdx.x, tid = threadIdx.x;
  __shared__ unsigned hist[256];
  __shared__ unsigned long long sh_pref;
  __shared__ unsigned sh_rem, sh_cnt;
  const float* sc = scores + b * 22500;
  if (tid == 0) { sh_pref = 0ull; sh_rem = 6000u; }
  __syncthreads();
  for (int pass = 0; pass < 6; ++pass) {
    const int shift = 40 - pass * 8;
    if (tid < 256) hist[tid] = 0u;
    __syncthreads();
    const unsigned long long pref = sh_pref;
    for (int j = tid; j < 22500; j += 1024) {
      unsigned long long key = key48(sc[j], j);
      if ((key >> (shift + 8)) == pref)
        atomicAdd(&hist[(unsigned)(key >> shift) & 255u], 1u);
    }
    __syncthreads();
    if (tid == 0) {
      unsigned rem = sh_rem;
      unsigned c = 0; int sel = 0;
      for (int bin = 255; bin >= 0; --bin) {
        unsigned nc = c + hist[bin];
        if (nc >= rem) { sel = bin; break; }
        c = nc;
      }
      sh_rem = rem - c;
      sh_pref = (sh_pref << 8) | (unsigned long long)sel;
    }
    __syncthreads();
  }
  const unsigned long long T = sh_pref;
  if (tid == 0) sh_cnt = 0u;
  __syncthreads();
  const float4* bx4 = (const float4*)boxes;
  float4* tb4 = (float4*)tbx;
  for (int j = tid; j < 22500; j += 1024) {
    unsigned long long key = key48(sc[j], j);
    if (key >= T) {
      unsigned slot = atomicAdd(&sh_cnt, 1u);
      if (slot < 6000u) {
        tsc[b * 6000 + slot] = sc[j];
        tidx[b * 6000 + slot] = j;
        tb4[b * 6000 + slot] = bx4[b * 22500 + j];
      }
    }
  }
}

// ------------------------------------------------------------------
// Rank-sort (unchanged, verified)
// ------------------------------------------------------------------
__global__ __launch_bounds__(256) void rank_kernel(
    const float* __restrict__ tsc, const int* __restrict__ tidx,
    const float* __restrict__ tbx,
    float* __restrict__ sbx, float* __restrict__ ssc) {
  const int b = blockIdx.y;
  const int c = blockIdx.x * 256 + threadIdx.x;
  const int lane = threadIdx.x & 63;
  const float* scb = tsc + b * 6000;
  const int* idb = tidx + b * 6000;
  unsigned long long kc = (c < 6000) ? key48(scb[c], idb[c]) : 0ull;
  int rank = 0;
  for (int t = 0; t < 94; ++t) {
    int j = t * 64 + lane;
    unsigned long long kj = (j < 6000) ? key48(scb[j], idb[j]) : 0ull;
    #pragma unroll
    for (int r = 0; r < 64; ++r) {
      unsigned long long kk = __shfl(kj, r);
      rank += (kk > kc) ? 1 : 0;
    }
  }
  if (c < 6000) {
    ((float4*)sbx)[b * 6000 + rank] = ((const float4*)tbx)[b * 6000 + c];
    ssc[b * 6000 + rank] = scb[c];
  }
}

// ------------------------------------------------------------------
// Suppression bitmask (unchanged, verified)
// ------------------------------------------------------------------
__global__ __launch_bounds__(256) void mask_kernel(
    const float* __restrict__ sbx, unsigned long long* __restrict__ mask) {
  const int b = blockIdx.y;
  const int row = blockIdx.x * 64 + (threadIdx.x & 63);
  const int wseg = threadIdx.x >> 6;
  __shared__ float4 jb[512];
  const float4* sb4 = (const float4*)sbx + (size_t)b * 6000;
  float4 rb = sb4[row < 6000 ? row : 5999];
  const float ra = (rb.z - rb.x) * (rb.w - rb.y);
  unsigned long long m[24];
  #pragma unroll
  for (int q = 0; q < 24; ++q) m[q] = 0ull;
  for (int jt = 0; jt < 12; ++jt) {
    __syncthreads();
    for (int s = threadIdx.x; s < 512; s += 256) {
      int j = jt * 512 + s;
      jb[s] = (j < 6000) ? sb4[j] : make_float4(0.f, 0.f, 0.f, 0.f);
    }
    __syncthreads();
    #pragma unroll
    for (int ww = 0; ww < 2; ++ww) {
      int w = jt * 8 + wseg * 2 + ww;
      if (w >= 94) continue;
      int j0 = (wseg * 2 + ww) * 64;
      unsigned long long bits = 0ull;
      #pragma unroll
      for (int u = 0; u < 64; ++u) {
        float4 bb = jb[j0 + u];
        float aj = (bb.z - bb.x) * (bb.w - bb.y);
        float yy1 = fmaxf(rb.x, bb.x), xx1 = fmaxf(rb.y, bb.y);
        float yy2 = fminf(rb.z, bb.z), xx2 = fminf(rb.w, bb.w);
        float inter = fmaxf(yy2 - yy1, 0.f) * fmaxf(xx2 - xx1, 0.f);
        float iou = inter / (((ra + aj) - inter) + 1e-9f);
        bits |= (iou > 0.7f) ? (1ull << u) : 0ull;
      }
      m[jt * 2 + ww] = bits;
    }
  }
  if (row < 6000) {
    unsigned long long* mr = mask + (size_t)(b * 6000 + row) * 94;
    #pragma unroll
    for (int jt = 0; jt < 12; ++jt)
      #pragma unroll
      for (int ww = 0; ww < 2; ++ww) {
        int w = jt * 8 + wseg * 2 + ww;
        if (w < 94) mr[w] = m[jt * 2 + ww];
      }
  }
}

// ------------------------------------------------------------------
// Greedy bitmask walk, chunked (unchanged, verified r12)
// ------------------------------------------------------------------
__global__ __launch_bounds__(64) void nmsbit_kernel(
    const float* __restrict__ ssc, const float* __restrict__ sbx,
    const unsigned long long* __restrict__ mask, float* __restrict__ out) {
  const int b = blockIdx.x, lane = threadIdx.x;
  __shared__ unsigned long long live[94];
  __shared__ int picks[300];
  int cnt = 0;
  for (int j = lane; j < 6000; j += 64)
    cnt += (ssc[b * 6000 + j] > NEGH) ? 1 : 0;
  #pragma unroll
  for (int off = 32; off > 0; off >>= 1) cnt += __shfl_down(cnt, off);
  const int nvalid = __shfl(cnt, 0);
  for (int w = lane; w < 94; w += 64) {
    int base = w * 64;
    unsigned long long mm;
    if (base + 64 <= nvalid) mm = ~0ull;
    else if (base >= nvalid) mm = 0ull;
    else mm = (~0ull) >> (64 - (nvalid - base));
    live[w] = mm;
  }
  __syncthreads();

  int np = 0;
  for (int c = 0; c < 94 && np < 300; ++c) {
    unsigned long long bits = live[c];
    if (bits == 0ull) continue;
    int row = c * 64 + lane;
    unsigned long long dw = (row < 6000)
        ? mask[(size_t)(b * 6000 + row) * 94 + c] : 0ull;
    unsigned long long prows = 0ull;
    while (bits != 0ull && np < 300) {
      int bpos = __ffsll(bits) - 1;
      if (lane == 0) picks[np] = c * 64 + bpos;
      np++;
      prows |= (1ull << bpos);
      unsigned long long dwb = __shfl(dw, bpos);
      bits &= ~dwb;
      bits &= ~(1ull << bpos);
    }
    unsigned long long acc0 = 0ull, acc1 = 0ull;
    unsigned long long pr = prows;
    while (pr != 0ull) {
      int bpos = __ffsll(pr) - 1; pr &= pr - 1ull;
      const unsigned long long* mr = mask + (size_t)(b * 6000 + c * 64 + bpos) * 94;
      acc0 |= mr[lane];
      if (lane < 30) acc1 |= mr[lane + 64];
    }
    if (prows != 0ull) {
      live[lane] &= ~acc0;
      if (lane < 30) live[lane + 64] &= ~acc1;
      __syncthreads();
    }
  }
  __syncthreads();

  float* rois = out;
  float* rsc  = out + 12000;
  for (int t = lane; t < 300; t += 64) {
    float* rp = rois + (size_t)(b * 300 + t) * 5;
    if (t < np) {
      int i = picks[t];
      float4 bb = ((const float4*)sbx)[b * 6000 + i];
      rp[0] = (float)b; rp[1] = bb.x; rp[2] = bb.y; rp[3] = bb.z; rp[4] = bb.w;
      rsc[b * 300 + t] = ssc[b * 6000 + i];
    } else {
      rp[0] = 0.f; rp[1] = 0.f; rp[2] = 0.f; rp[3] = 0.f; rp[4] = 0.f;
      rsc[b * 300 + t] = 0.f;
    }
  }
}

// ------------------------------------------------------------------
extern "C" void kernel_launch(void* const* d_in, const int* in_sizes, int n_in,
                              void* d_out, int out_size, void* d_ws, size_t ws_size,
                              hipStream_t stream) {
  const float* feat = (const float*)d_in[0];
  const float* W1   = (const float*)d_in[1];
  const float* b1   = (const float*)d_in[2];
  const float* Wreg = (const float*)d_in[3];
  const float* breg = (const float*)d_in[4];
  const float* Wcls = (const float*)d_in[5];
  const float* bcls = (const float*)d_in[6];
  float* out = (float*)d_out;
  float* ws  = (float*)d_ws;

  // ws (floats): W1pack 3,538,944 | conv1 10,240,000 (mask aliases) |
  // boxes/sbx/ssc | scores | tbx | tsc | tidx | Wt 27,648
  // total 14,994,592 f = 59,978,368 B (ws proven >= 94.7 MB in r3/r4)
  const size_t NEED = 59978368ull;
  if (ws_size >= NEED) {
    unsigned* W1pack = (unsigned*)ws;
    float* conv1  = ws + 3538944;
    unsigned long long* mask = (unsigned long long*)(ws + 3538944);
    float* boxes  = ws + 13778944;
    float* sbx    = ws + 13778944;
    float* ssc    = ws + 13970944;
    float* scores = ws + 14498944;
    float* tbx    = ws + 14678944;
    float* tsc    = ws + 14870944;
    int*   tidx   = (int*)(ws + 14918944);
    float* Wt     = ws + 14966944;

    w1pack_kernel<<<512, 256, 0, stream>>>(W1, W1pack);
    wtpack_kernel<<<108, 256, 0, stream>>>(Wreg, Wcls, Wt);
    conv_mfma_kernel<<<640, 256, 0, stream>>>(feat, (const char*)W1pack, b1, conv1);
    heads_kernel<<<1250, 256, 0, stream>>>(conv1, Wt, breg, bcls, boxes, scores);
    topk_kernel<<<8, 1024, 0, stream>>>(scores, boxes, tsc, tbx, tidx);
    rank_kernel<<<dim3(24, 8), 256, 0, stream>>>(tsc, tidx, tbx, sbx, ssc);
    mask_kernel<<<dim3(94, 8), 256, 0, stream>>>(sbx, mask);
    nmsbit_kernel<<<8, 64, 0, stream>>>(ssc, sbx, mask, out);
  }
}